// Round 1
// baseline (135.204 us; speedup 1.0000x reference)
//
#include <hip/hip_runtime.h>
#include <math.h>

// AlphaBetaFilter: per-(b,c) linear recurrence over T steps.
//   s_t = M s_{t-1} + v * x_t,  M = [[1-a, 1-a], [-a*b, 1-a*b]], v = (a, a*b)
//   out_t = L_t (first state component); s_0 = (x_0, 0).
// Chunked parallel scan: K chunks of S steps each.

#define B_ 32
#define T_ 4096
#define C_ 128
#define K_ 64            // chunks per sequence
#define S_ (T_ / K_)     // 64 steps per chunk (2^6 -> 6 squarings for M^S)

__device__ __forceinline__ float sig_clamp(float z) {
    float s = 1.0f / (1.0f + expf(-z));
    return fminf(fmaxf(s, 1.0e-4f), 1.0f - 1.0e-4f);
}

// Phase 1: per-chunk affine offset w_k (zero-state run). Chunk 0 = exact end state.
__global__ __launch_bounds__(C_) void p1_chunk_offsets(
        const float* __restrict__ x,
        const float* __restrict__ logit_alpha,
        const float* __restrict__ logit_beta,
        float2* __restrict__ w) {
    const int blk = blockIdx.x;
    const int b = blk / K_;
    const int k = blk % K_;
    const int c = threadIdx.x;

    const float a  = sig_clamp(logit_alpha[c]);
    const float bb = sig_clamp(logit_beta[c]);

    const float* xp = x + ((size_t)b * T_ + (size_t)k * S_) * C_ + c;

    float L, sl;
    int t0;
    if (k == 0) {
        L = xp[0];            // s_0 = (x_0, 0)
        sl = 0.0f;
        xp += C_;
        t0 = 1;
    } else {
        L = 0.0f;             // zero-state: accumulates affine part only
        sl = 0.0f;
        t0 = 0;
    }
    #pragma unroll 8
    for (int t = t0; t < S_; ++t) {
        const float xv = *xp;
        xp += C_;
        const float pred = L + sl;
        const float Ln = pred + a * (xv - pred);
        sl = sl + bb * (Ln - L - sl);
        L = Ln;
    }
    w[((size_t)b * K_ + k) * C_ + c] = make_float2(L, sl);
}

// Phase 2: sequential scan over chunks per (b,c); emits chunk start states.
__global__ __launch_bounds__(256) void p2_chunk_scan(
        const float2* __restrict__ w,
        const float* __restrict__ logit_alpha,
        const float* __restrict__ logit_beta,
        float2* __restrict__ sstart) {
    const int tid = blockIdx.x * blockDim.x + threadIdx.x;
    if (tid >= B_ * C_) return;
    const int b = tid / C_;
    const int c = tid % C_;

    const float a  = sig_clamp(logit_alpha[c]);
    const float bb = sig_clamp(logit_beta[c]);

    // M^S by repeated squaring (S = 64 = 2^6)
    float m00 = 1.0f - a, m01 = 1.0f - a;
    float m10 = -a * bb,  m11 = 1.0f - a * bb;
    #pragma unroll
    for (int i = 0; i < 6; ++i) {
        const float n00 = m00 * m00 + m01 * m10;
        const float n01 = m00 * m01 + m01 * m11;
        const float n10 = m10 * m00 + m11 * m10;
        const float n11 = m10 * m01 + m11 * m11;
        m00 = n00; m01 = n01; m10 = n10; m11 = n11;
    }

    const size_t base = (size_t)b * K_ * C_ + c;
    float2 s = w[base];     // exact end state of chunk 0
    #pragma unroll 8
    for (int k = 1; k < K_; ++k) {
        sstart[base + (size_t)k * C_] = s;
        const float2 wk = w[base + (size_t)k * C_];
        const float L  = m00 * s.x + m01 * s.y + wk.x;
        const float sl = m10 * s.x + m11 * s.y + wk.y;
        s = make_float2(L, sl);
    }
}

// Phase 3: replay each chunk from its start state, writing outputs.
__global__ __launch_bounds__(C_) void p3_emit(
        const float* __restrict__ x,
        const float* __restrict__ logit_alpha,
        const float* __restrict__ logit_beta,
        const float2* __restrict__ sstart,
        float* __restrict__ out) {
    const int blk = blockIdx.x;
    const int b = blk / K_;
    const int k = blk % K_;
    const int c = threadIdx.x;

    const float a  = sig_clamp(logit_alpha[c]);
    const float bb = sig_clamp(logit_beta[c]);

    const size_t off = ((size_t)b * T_ + (size_t)k * S_) * C_ + c;
    const float* xp = x + off;
    float* op = out + off;

    float L, sl;
    int t0;
    if (k == 0) {
        L = xp[0];
        sl = 0.0f;
        op[0] = L;
        xp += C_; op += C_;
        t0 = 1;
    } else {
        const float2 s = sstart[((size_t)b * K_ + k) * C_ + c];
        L = s.x; sl = s.y;
        t0 = 0;
    }
    #pragma unroll 8
    for (int t = t0; t < S_; ++t) {
        const float xv = *xp;
        xp += C_;
        const float pred = L + sl;
        const float Ln = pred + a * (xv - pred);
        sl = sl + bb * (Ln - L - sl);
        L = Ln;
        *op = L;
        op += C_;
    }
}

// Fallback: fully sequential per-(b,c) thread (used only if ws too small).
__global__ void seq_fallback(
        const float* __restrict__ x,
        const float* __restrict__ logit_alpha,
        const float* __restrict__ logit_beta,
        float* __restrict__ out) {
    const int tid = blockIdx.x * blockDim.x + threadIdx.x;
    if (tid >= B_ * C_) return;
    const int b = tid / C_;
    const int c = tid % C_;
    const float a  = sig_clamp(logit_alpha[c]);
    const float bb = sig_clamp(logit_beta[c]);
    const float* xp = x + (size_t)b * T_ * C_ + c;
    float* op = out + (size_t)b * T_ * C_ + c;
    float L = xp[0], sl = 0.0f;
    op[0] = L;
    for (int t = 1; t < T_; ++t) {
        const float xv = xp[(size_t)t * C_];
        const float pred = L + sl;
        const float Ln = pred + a * (xv - pred);
        sl = sl + bb * (Ln - L - sl);
        L = Ln;
        op[(size_t)t * C_] = L;
    }
}

extern "C" void kernel_launch(void* const* d_in, const int* in_sizes, int n_in,
                              void* d_out, int out_size, void* d_ws, size_t ws_size,
                              hipStream_t stream) {
    const float* x  = (const float*)d_in[0];
    const float* la = (const float*)d_in[1];
    const float* lb = (const float*)d_in[2];
    float* out = (float*)d_out;

    const size_t n_state = (size_t)B_ * K_ * C_;           // float2 entries per array
    const size_t need = 2 * n_state * sizeof(float2);      // w + sstart = 4 MiB

    if (ws_size >= need) {
        float2* w      = (float2*)d_ws;
        float2* sstart = w + n_state;
        p1_chunk_offsets<<<B_ * K_, C_, 0, stream>>>(x, la, lb, w);
        p2_chunk_scan<<<(B_ * C_ + 255) / 256, 256, 0, stream>>>(w, la, lb, sstart);
        p3_emit<<<B_ * K_, C_, 0, stream>>>(x, la, lb, sstart, out);
    } else {
        seq_fallback<<<(B_ * C_ + 255) / 256, 256, 0, stream>>>(x, la, lb, out);
    }
}

// Round 2
// 130.405 us; speedup vs baseline: 1.0368x; 1.0368x over previous
//
#include <hip/hip_runtime.h>
#include <math.h>

// AlphaBetaFilter: per-(b,c) linear recurrence over T steps.
//   pred = L + sl;  g = a*(x - pred);  L' = pred + g;  sl' = sl + b*g
// Linear in state s=(L,sl):  s_t = M s_{t-1} + v x_t,
//   M = [[1-a,1-a],[-ab,1-ab]], v=(a,ab);  s_0=(x_0,0).
// 2-kernel chunked scan, K=64 chunks of S=64:
//   A: per-chunk zero-state run -> affine offset w[b,k]   (chunk0 = exact)
//   B: per-chunk prefix scan of w with M^S, then replay chunk emitting out.
// Each thread owns TWO adjacent channels (float2 loads, 2 indep chains).

#define B_ 32
#define T_ 4096
#define C_ 128
#define K_ 64
#define S_ (T_ / K_)      // 64
#define C2 (C_ / 2)       // 64 float2 lanes per row
#define NCHUNK (B_ * K_)  // 2048

__device__ __forceinline__ float sig_clamp(float z) {
    float s = 1.0f / (1.0f + expf(-z));
    return fminf(fmaxf(s, 1.0e-4f), 1.0f - 1.0e-4f);
}

#define STEP(xv0, xv1)                                   \
    {                                                    \
        const float p0 = L0 + sl0;                       \
        const float p1 = L1 + sl1;                       \
        const float g0 = a0 * ((xv0) - p0);              \
        const float g1 = a1 * ((xv1) - p1);              \
        L0 = p0 + g0;  sl0 = fmaf(b0, g0, sl0);          \
        L1 = p1 + g1;  sl1 = fmaf(b1, g1, sl1);          \
    }

// Kernel A: per-chunk affine offsets (zero initial state except chunk 0).
__global__ __launch_bounds__(256) void p1_offsets(
        const float* __restrict__ x,
        const float* __restrict__ logit_alpha,
        const float* __restrict__ logit_beta,
        float4* __restrict__ w) {
    const int tid = threadIdx.x & 63;              // float2 lane within chunk
    const int chunk = blockIdx.x * 4 + (threadIdx.x >> 6);
    const int b = chunk >> 6;
    const int k = chunk & (K_ - 1);

    const float2 la2 = ((const float2*)logit_alpha)[tid];
    const float2 lb2 = ((const float2*)logit_beta)[tid];
    const float a0 = sig_clamp(la2.x), a1 = sig_clamp(la2.y);
    const float b0 = sig_clamp(lb2.x), b1 = sig_clamp(lb2.y);

    const float2* xp = (const float2*)x + ((size_t)b * T_ + (size_t)k * S_) * C2 + tid;

    float L0, sl0 = 0.0f, L1, sl1 = 0.0f;
    int t0;
    if (k == 0) {
        const float2 v = xp[0];
        L0 = v.x; L1 = v.y;
        xp += C2;
        t0 = 1;
    } else {
        L0 = 0.0f; L1 = 0.0f;
        t0 = 0;
    }
    #pragma unroll 8
    for (int t = t0; t < S_; ++t) {
        const float2 xv = *xp;
        xp += C2;
        STEP(xv.x, xv.y);
    }
    w[(size_t)chunk * 64 + tid] = make_float4(L0, sl0, L1, sl1);
}

// Kernel B: per-block prefix scan of w (with M^S), then replay chunk.
__global__ __launch_bounds__(256) void p2_emit(
        const float* __restrict__ x,
        const float* __restrict__ logit_alpha,
        const float* __restrict__ logit_beta,
        const float4* __restrict__ w,
        float* __restrict__ out) {
    const int tid = threadIdx.x & 63;
    // reverse order: largest-k chunks (most prefix work) dispatch first
    const int chunk = (NCHUNK - 1) - (blockIdx.x * 4 + (threadIdx.x >> 6));
    const int b = chunk >> 6;
    const int k = chunk & (K_ - 1);

    const float2 la2 = ((const float2*)logit_alpha)[tid];
    const float2 lb2 = ((const float2*)logit_beta)[tid];
    const float a0 = sig_clamp(la2.x), a1 = sig_clamp(la2.y);
    const float b0 = sig_clamp(lb2.x), b1 = sig_clamp(lb2.y);

    const size_t off = ((size_t)b * T_ + (size_t)k * S_) * C2 + tid;
    const float2* xp = (const float2*)x + off;
    float2* op = (float2*)out + off;

    float L0, sl0, L1, sl1;
    int t0;
    if (k == 0) {
        const float2 v = xp[0];
        L0 = v.x; L1 = v.y; sl0 = 0.0f; sl1 = 0.0f;
        op[0] = make_float2(L0, L1);
        xp += C2; op += C2;
        t0 = 1;
    } else {
        // M^S per channel via 6 squarings (S = 64 = 2^6)
        float m00_0 = 1.0f - a0, m01_0 = 1.0f - a0;
        float m10_0 = -a0 * b0,  m11_0 = 1.0f - a0 * b0;
        float m00_1 = 1.0f - a1, m01_1 = 1.0f - a1;
        float m10_1 = -a1 * b1,  m11_1 = 1.0f - a1 * b1;
        #pragma unroll
        for (int i = 0; i < 6; ++i) {
            float n00 = m00_0 * m00_0 + m01_0 * m10_0;
            float n01 = m00_0 * m01_0 + m01_0 * m11_0;
            float n10 = m10_0 * m00_0 + m11_0 * m10_0;
            float n11 = m10_0 * m01_0 + m11_0 * m11_0;
            m00_0 = n00; m01_0 = n01; m10_0 = n10; m11_0 = n11;
            n00 = m00_1 * m00_1 + m01_1 * m10_1;
            n01 = m00_1 * m01_1 + m01_1 * m11_1;
            n10 = m10_1 * m00_1 + m11_1 * m10_1;
            n11 = m10_1 * m01_1 + m11_1 * m11_1;
            m00_1 = n00; m01_1 = n01; m10_1 = n10; m11_1 = n11;
        }
        // prefix scan over chunks 0..k-1 of this batch row
        const float4* wp = w + (size_t)b * K_ * 64 + tid;
        float4 s = wp[0];
        #pragma unroll 4
        for (int j = 1; j < k; ++j) {
            const float4 wj = wp[(size_t)j * 64];
            const float nx = m00_0 * s.x + m01_0 * s.y + wj.x;
            const float ny = m10_0 * s.x + m11_0 * s.y + wj.y;
            const float nz = m00_1 * s.z + m01_1 * s.w + wj.z;
            const float nw = m10_1 * s.z + m11_1 * s.w + wj.w;
            s = make_float4(nx, ny, nz, nw);
        }
        L0 = s.x; sl0 = s.y; L1 = s.z; sl1 = s.w;
        t0 = 0;
    }

    #pragma unroll 8
    for (int t = t0; t < S_; ++t) {
        const float2 xv = *xp;
        xp += C2;
        STEP(xv.x, xv.y);
        *op = make_float2(L0, L1);
        op += C2;
    }
}

// Fallback: fully sequential per-(b,c) thread (used only if ws too small).
__global__ void seq_fallback(
        const float* __restrict__ x,
        const float* __restrict__ logit_alpha,
        const float* __restrict__ logit_beta,
        float* __restrict__ out) {
    const int tid = blockIdx.x * blockDim.x + threadIdx.x;
    if (tid >= B_ * C_) return;
    const int b = tid / C_;
    const int c = tid % C_;
    const float a0 = sig_clamp(logit_alpha[c]);
    const float b0 = sig_clamp(logit_beta[c]);
    const float* xp = x + (size_t)b * T_ * C_ + c;
    float* op = out + (size_t)b * T_ * C_ + c;
    float L0 = xp[0], sl0 = 0.0f;
    op[0] = L0;
    for (int t = 1; t < T_; ++t) {
        const float xv = xp[(size_t)t * C_];
        const float p0 = L0 + sl0;
        const float g0 = a0 * (xv - p0);
        L0 = p0 + g0;
        sl0 = fmaf(b0, g0, sl0);
        op[(size_t)t * C_] = L0;
    }
}

extern "C" void kernel_launch(void* const* d_in, const int* in_sizes, int n_in,
                              void* d_out, int out_size, void* d_ws, size_t ws_size,
                              hipStream_t stream) {
    const float* x  = (const float*)d_in[0];
    const float* la = (const float*)d_in[1];
    const float* lb = (const float*)d_in[2];
    float* out = (float*)d_out;

    const size_t need = (size_t)NCHUNK * 64 * sizeof(float4);  // 2 MiB

    if (ws_size >= need) {
        float4* w = (float4*)d_ws;
        p1_offsets<<<NCHUNK / 4, 256, 0, stream>>>(x, la, lb, w);
        p2_emit<<<NCHUNK / 4, 256, 0, stream>>>(x, la, lb, w, out);
    } else {
        seq_fallback<<<(B_ * C_ + 255) / 256, 256, 0, stream>>>(x, la, lb, out);
    }
}